// Round 12
// baseline (337.253 us; speedup 1.0000x reference)
//
#include <hip/hip_runtime.h>
#include <stdint.h>

#define N_NODES 50000
#define N_PAD   50048     // 391 * 128
#define F_IN 512
#define H_DIM 256
#define C_DIM 16
#define SLAB ((size_t)N_PAD * 32)   // elems per 32-feature slab

typedef __attribute__((ext_vector_type(8))) short short8;
typedef __attribute__((ext_vector_type(4))) float f32x4;
typedef __attribute__((ext_vector_type(4))) unsigned short us4;
typedef __attribute__((ext_vector_type(8))) unsigned short us8;

__device__ inline float bf2f(unsigned short u) {
    return __uint_as_float(((uint32_t)u) << 16);
}
__device__ inline unsigned short f2bf(float f) {
    uint32_t u = __float_as_uint(f);
    u += 0x7FFFu + ((u >> 16) & 1u);   // round-to-nearest-even
    return (unsigned short)(u >> 16);
}
__device__ inline unsigned short hx(float f) {   // truncating bf16 (1 op)
    return (unsigned short)(__float_as_uint(f) >> 16);
}
__device__ inline int eidx(const void* p, long long i, int is64) {
    return is64 ? (int)((const long long*)p)[i] : ((const int*)p)[i];
}

// CSR row bounds: rowoff = per-512-chunk exclusive sums, bsum = scanned
// chunk offsets (scan2).
__device__ inline int row_beg(const int* ro, const int* bs, int n) {
    return ro[n] + bs[n >> 9];
}
__device__ inline int row_end(const int* ro, const int* bs, int n, int E) {
    return (n + 1 < N_NODES) ? ro[n + 1] + bs[(n + 1) >> 9] : E;
}

// async global->LDS, 16B per lane, linear LDS dest (wave base + lane*16)
#define GLOAD16(gp, lp)                                                       \
    __builtin_amdgcn_global_load_lds(                                         \
        (const __attribute__((address_space(1))) void*)(gp),                  \
        (__attribute__((address_space(3))) void*)(lp), 16, 0, 0)

// ---------- fused prep: dtype detect + W transpose-convert + cnt/cur zero --

__global__ void prep_k(const void* ei, int* flag,
                       const float* w1, unsigned short* w1t,
                       const float* w2, unsigned short* w2t,
                       int* cnt, int* cur) {
    int i = blockIdx.x * 256 + threadIdx.x;
    if (i == 0) {
        const uint32_t* w = (const uint32_t*)ei;
        int is64 = 1;
        for (int j = 1; j < 128; j += 2)
            if (w[j] != 0u) { is64 = 0; break; }
        *flag = is64;
    }
    if (i < N_NODES) { cnt[i] = 0; cur[i] = 0; }
    if (i < F_IN * H_DIM) {
        int k = i / H_DIM, n = i % H_DIM;
        w1t[n * F_IN + k] = f2bf(w1[i]);
    }
    if (i < H_DIM * C_DIM) {
        int k = i / C_DIM, n = i % C_DIM;
        w2t[n * H_DIM + k] = f2bf(w2[i]);
    }
}

// ---------- graph build (r9 structure) ----------

__global__ void hist_k(const void* ei, const int* flag, int* cnt, long long E) {
    long long e = (long long)blockIdx.x * 256 + threadIdx.x;
    if (e >= E) return;
    int d = eidx(ei, E + e, *flag);
    atomicAdd(&cnt[d], 1);
}

__global__ __launch_bounds__(512) void scan1_k(const int* cnt, int* rowoff, int* bsum,
                                               float* dinv, int n) {
    __shared__ int s[512];
    int t = threadIdx.x;
    int i = blockIdx.x * 512 + t;
    int v = (i < n) ? cnt[i] : 0;
    s[t] = v;
    __syncthreads();
    for (int off = 1; off < 512; off <<= 1) {
        int add = (t >= off) ? s[t - off] : 0;
        __syncthreads();
        s[t] += add;
        __syncthreads();
    }
    if (i < n) {
        rowoff[i] = s[t] - v;                 // exclusive within chunk
        dinv[i] = rsqrtf((float)(v + 1));     // +1 self loop
    }
    if (t == 511) bsum[blockIdx.x] = s[511];
}

__global__ void scan2_k(int* bsum, int nb) {
    __shared__ int s[128];
    int t = threadIdx.x;
    int v = (t < nb) ? bsum[t] : 0;
    s[t] = v;
    __syncthreads();
    for (int off = 1; off < 128; off <<= 1) {
        int add = (t >= off) ? s[t - off] : 0;
        __syncthreads();
        s[t] += add;
        __syncthreads();
    }
    if (t < nb) bsum[t] = s[t] - v;     // exclusive chunk offsets
}

__global__ void scatter_k(const void* ei, const int* flag, const float* dinv,
                          const int* rowoff, const int* bsum, int* cur,
                          long long E, int2* colnorm) {
    long long e = (long long)blockIdx.x * 256 + threadIdx.x;
    if (e >= E) return;
    int is64 = *flag;
    int s = eidx(ei, e, is64);
    int d = eidx(ei, E + e, is64);
    int pos = row_beg(rowoff, bsum, d) + atomicAdd(&cur[d], 1);
    float nrm = dinv[s] * dinv[d];
    int2 cn;
    cn.x = s;
    cn.y = __float_as_int(nrm);
    colnorm[pos] = cn;
}

// ---------- GEMM1: h1(slabs) = bf16(x @ W1) — r9 counted-vmcnt pipeline ----
// Epilogue writes h1 into 8 feature-slabs: h1s[s][node][32], s = feat>>5.

__global__ __launch_bounds__(512, 4) void gemm1_k(const float* __restrict__ x,
                                                  const unsigned short* __restrict__ w1t,
                                                  unsigned short* __restrict__ h1s) {
    __shared__ __align__(16) float          Asf[2][128 * 32];  // 32 KB
    __shared__ __align__(16) unsigned short Bs[2][256 * 32];   // 32 KB

    const int t = threadIdx.x;
    const int wv = t >> 6, lane = t & 63;
    const int lg = lane >> 4, lr = lane & 15;
    const int wm = wv >> 2, wn = wv & 3;

    const int arow0 = t >> 3;
    const int achk = (t & 7) ^ (arow0 & 7);
    size_t g0 = (size_t)blockIdx.x * 128 + arow0;
    size_t g1 = g0 + 64;
    if (g0 > N_NODES - 1) g0 = N_NODES - 1;
    if (g1 > N_NODES - 1) g1 = N_NODES - 1;
    const float* asrc0 = x + g0 * F_IN + achk * 4;
    const float* asrc1 = x + g1 * F_IN + achk * 4;
    const unsigned short* bsrc0 = w1t + (size_t)(t >> 2) * F_IN + (t & 3) * 8;
    const unsigned short* bsrc1 = bsrc0 + 128 * F_IN;

#define STAGE(bf, ks)                                                         \
    do { const int _o = (ks) * 32;                                            \
        GLOAD16(asrc0 + _o, &Asf[bf][t * 4]);                                 \
        GLOAD16(asrc1 + _o, &Asf[bf][t * 4 + 2048]);                          \
        GLOAD16(bsrc0 + _o, &Bs[bf][t * 8]);                                  \
        GLOAD16(bsrc1 + _o, &Bs[bf][(t + 512) * 8]);                          \
    } while (0)

    f32x4 acc[4][4] = {};

    STAGE(0, 0);                       // 4 outstanding

    for (int ks = 0; ks < 16; ++ks) {
        const int bf = ks & 1;
        if (ks < 15) {
            STAGE(bf ^ 1, ks + 1);     // <=8 outstanding
            asm volatile("s_waitcnt vmcnt(4)" ::: "memory");  // buf-ks landed
        } else {
            asm volatile("s_waitcnt vmcnt(0)" ::: "memory");
        }
        __builtin_amdgcn_sched_barrier(0);
        __builtin_amdgcn_s_barrier();  // bar1: buf-ks visible to all waves

        short8 afr[4], bfr[4];
#pragma unroll
        for (int mi = 0; mi < 4; ++mi) {
            const int r = wm * 64 + mi * 16 + lr;
            const int s = r & 7;
            const float* base = &Asf[bf][r * 32];
            f32x4 lo = *(const f32x4*)(base + (((lg * 2) ^ s) * 4));
            f32x4 hi = *(const f32x4*)(base + (((lg * 2 + 1) ^ s) * 4));
            short8 a;
            a[0] = (short)hx(lo[0]); a[1] = (short)hx(lo[1]);
            a[2] = (short)hx(lo[2]); a[3] = (short)hx(lo[3]);
            a[4] = (short)hx(hi[0]); a[5] = (short)hx(hi[1]);
            a[6] = (short)hx(hi[2]); a[7] = (short)hx(hi[3]);
            afr[mi] = a;
        }
#pragma unroll
        for (int ni = 0; ni < 4; ++ni)
            bfr[ni] = *(const short8*)&Bs[bf][(wn * 64 + ni * 16 + lr) * 32 + lg * 8];
#pragma unroll
        for (int mi = 0; mi < 4; ++mi)
#pragma unroll
            for (int ni = 0; ni < 4; ++ni)
                acc[mi][ni] = __builtin_amdgcn_mfma_f32_16x16x32_bf16(
                    afr[mi], bfr[ni], acc[mi][ni], 0, 0, 0);

        asm volatile("s_waitcnt lgkmcnt(0)" ::: "memory");
        __builtin_amdgcn_sched_barrier(0);
        __builtin_amdgcn_s_barrier();  // bar2: safe to overwrite next buffer
    }
#undef STAGE

    // C layout: col=lane&15, row=(lane>>4)*4+reg. Slab write:
    // feat = wn*64+ni*16+lr -> slab s=wn*2+(ni>>1), col c=(ni&1)*16+lr.
    const size_t rbase = (size_t)blockIdx.x * 128 + wm * 64 + lg * 4;
#pragma unroll
    for (int mi = 0; mi < 4; ++mi)
#pragma unroll
        for (int ni = 0; ni < 4; ++ni) {
            const int s = wn * 2 + (ni >> 1);
            const int c = (ni & 1) * 16 + lr;
            unsigned short* dst = h1s + s * SLAB + c;
#pragma unroll
            for (int j = 0; j < 4; ++j)
                dst[(rbase + mi * 16 + j) * 32] = f2bf(acc[mi][ni][j]);
        }
}

// ---------- Aggregation layer 1, slab-partitioned for XCD L2 residency ----
// slice = blockIdx&7 -> (round-robin) XCD s only gathers slab s (3.2MB < 4MB
// L2, no cross-slab line sharing). colnorm/rowoff via NONTEMPORAL loads and
// h1a via nontemporal stores so streams don't evict the slab.
// 1 wave per (node, slice): lanes = 4 edge-slots x 16 feature-pairs,
// 2-deep ILP, shfl_xor(16/32) reduce over edge-slots.

__global__ __launch_bounds__(256) void agg1_k(const unsigned short* __restrict__ h1s,
                                              const int* __restrict__ rowoff,
                                              const int* __restrict__ bsum,
                                              const int2* __restrict__ colnorm,
                                              const float* __restrict__ dinv,
                                              const float* __restrict__ b1,
                                              unsigned short* __restrict__ h1as,
                                              int E) {
    const int slice = blockIdx.x & 7;
    const int nb = blockIdx.x >> 3;
    const int wv = threadIdx.x >> 6, lane = threadIdx.x & 63;
    const int node = nb * 4 + wv;
    if (node >= N_NODES) return;
    const int eg = lane >> 4;               // edge slot 0..3
    const int fp = lane & 15;               // feature pair (2 bf16)
    const unsigned short* slab = h1s + (size_t)slice * SLAB;

    const int beg = row_beg(rowoff, bsum, node);
    const int end = row_end(rowoff, bsum, node, E);
    float a0 = 0.f, a1 = 0.f;

    int e = beg + eg;
    while (e + 4 < end) {                   // 8 edges in flight per wave
        long long cc0 = __builtin_nontemporal_load((const long long*)&colnorm[e]);
        long long cc1 = __builtin_nontemporal_load((const long long*)&colnorm[e + 4]);
        int s0 = (int)cc0, s1 = (int)cc1;
        float n0 = __uint_as_float((uint32_t)((unsigned long long)cc0 >> 32));
        float n1 = __uint_as_float((uint32_t)((unsigned long long)cc1 >> 32));
        uint32_t v0 = *(const uint32_t*)(slab + (size_t)s0 * 32 + fp * 2);
        uint32_t v1 = *(const uint32_t*)(slab + (size_t)s1 * 32 + fp * 2);
        a0 += n0 * bf2f(v0 & 0xffff) + n1 * bf2f(v1 & 0xffff);
        a1 += n0 * bf2f(v0 >> 16) + n1 * bf2f(v1 >> 16);
        e += 8;
    }
    while (e < end) {
        long long cc0 = __builtin_nontemporal_load((const long long*)&colnorm[e]);
        int s0 = (int)cc0;
        float n0 = __uint_as_float((uint32_t)((unsigned long long)cc0 >> 32));
        uint32_t v0 = *(const uint32_t*)(slab + (size_t)s0 * 32 + fp * 2);
        a0 += n0 * bf2f(v0 & 0xffff);
        a1 += n0 * bf2f(v0 >> 16);
        e += 4;
    }
    // reduce over edge slots (lane bits 4,5)
    a0 += __shfl_xor(a0, 16);
    a1 += __shfl_xor(a1, 16);
    a0 += __shfl_xor(a0, 32);
    a1 += __shfl_xor(a1, 32);

    if (eg == 0) {
        float dn = dinv[node];
        float sn = dn * dn;
        uint32_t vs = *(const uint32_t*)(slab + (size_t)node * 32 + fp * 2);
        float2 bb = *(const float2*)(b1 + slice * 32 + fp * 2);
        a0 = fmaxf(a0 + sn * bf2f(vs & 0xffff) + bb.x, 0.f);
        a1 = fmaxf(a1 + sn * bf2f(vs >> 16) + bb.y, 0.f);
        uint32_t o = (uint32_t)f2bf(a0) | ((uint32_t)f2bf(a1) << 16);
        uint32_t* dst = (uint32_t*)(h1as + (size_t)slice * SLAB +
                                    (size_t)node * 32 + fp * 2);
        __builtin_nontemporal_store(o, dst);
    }
}

// ---------- GEMM2: h2 = h1a(slabs) @ W2 (k-step ks == slab ks) -------------

__global__ __launch_bounds__(256) void gemm2_k(const unsigned short* __restrict__ h1as,
                                               const unsigned short* __restrict__ w2t,
                                               float* __restrict__ h2) {
    int t = threadIdx.x;
    int wv = t >> 6, lane = t & 63, lg = lane >> 4, lr = lane & 15;
    int rbase = blockIdx.x * 64 + wv * 16;
    int rr = rbase + lr;
    int rc = rr < N_NODES ? rr : N_NODES - 1;
    f32x4 acc = {0.f, 0.f, 0.f, 0.f};
#pragma unroll
    for (int ks = 0; ks < 8; ++ks) {
        short8 a = *(const short8*)(h1as + (size_t)ks * SLAB + (size_t)rc * 32 + lg * 8);
        short8 b = *(const short8*)(w2t + lr * H_DIM + ks * 32 + lg * 8);
        acc = __builtin_amdgcn_mfma_f32_16x16x32_bf16(a, b, acc, 0, 0, 0);
    }
#pragma unroll
    for (int j = 0; j < 4; ++j) {
        int row = rbase + lg * 4 + j;
        if (row < N_NODES) h2[(long long)row * C_DIM + lr] = acc[j];
    }
}

// ---------- Aggregation layer 2: out = A_norm @ h2 + b2 (fp32) ----------

__global__ __launch_bounds__(256) void agg2_k(const float* __restrict__ h2,
                                              const int* __restrict__ rowoff,
                                              const int* __restrict__ bsum,
                                              const int2* __restrict__ colnorm,
                                              const float* __restrict__ dinv,
                                              const float* __restrict__ b2,
                                              float* __restrict__ out, int E) {
    int g = threadIdx.x >> 4, c = threadIdx.x & 15;
    int node = blockIdx.x * 16 + g;
    if (node >= N_NODES) return;
    int beg = row_beg(rowoff, bsum, node);
    int end = row_end(rowoff, bsum, node, E);
    float acc = 0.f;
    int e = beg;
    for (; e + 3 < end; e += 4) {
        int2 cn0 = colnorm[e];
        int2 cn1 = colnorm[e + 1];
        int2 cn2 = colnorm[e + 2];
        int2 cn3 = colnorm[e + 3];
        float v0 = h2[(long long)cn0.x * C_DIM + c];
        float v1 = h2[(long long)cn1.x * C_DIM + c];
        float v2 = h2[(long long)cn2.x * C_DIM + c];
        float v3 = h2[(long long)cn3.x * C_DIM + c];
        acc += __int_as_float(cn0.y) * v0 + __int_as_float(cn1.y) * v1
             + __int_as_float(cn2.y) * v2 + __int_as_float(cn3.y) * v3;
    }
    for (; e < end; ++e) {
        int2 cn = colnorm[e];
        acc += __int_as_float(cn.y) * h2[(long long)cn.x * C_DIM + c];
    }
    float dn = dinv[node];
    acc += dn * dn * h2[(long long)node * C_DIM + c];
    out[(long long)node * C_DIM + c] = acc + b2[c];
}

// ---------- launch ----------

extern "C" void kernel_launch(void* const* d_in, const int* in_sizes, int n_in,
                              void* d_out, int out_size, void* d_ws, size_t ws_size,
                              hipStream_t stream) {
    const float* x  = (const float*)d_in[0];
    const void*  ei = d_in[1];
    const float* W1 = (const float*)d_in[2];
    const float* b1 = (const float*)d_in[3];
    const float* W2 = (const float*)d_in[4];
    const float* b2 = (const float*)d_in[5];
    float* out = (float*)d_out;
    long long E = (long long)in_sizes[1] / 2;

    char* w = (char*)d_ws;
    auto alloc = [&](size_t bytes) -> char* {
        char* p = w;
        w += (bytes + 255) & ~(size_t)255;
        return p;
    };
    int*   flag    = (int*)   alloc(4);
    int*   cnt     = (int*)   alloc((size_t)N_NODES * 4);
    int*   cur     = (int*)   alloc((size_t)N_NODES * 4);
    float* dinv    = (float*) alloc((size_t)N_NODES * 4);
    int*   rowoff  = (int*)   alloc((size_t)N_NODES * 4);
    int*   bsum    = (int*)   alloc(512 * 4);
    int2*  colnorm = (int2*)  alloc((size_t)E * 8);
    unsigned short* w1t  = (unsigned short*)alloc((size_t)H_DIM * F_IN * 2);
    unsigned short* w2t  = (unsigned short*)alloc((size_t)C_DIM * H_DIM * 2);
    unsigned short* h1s  = (unsigned short*)alloc(8 * SLAB * 2);   // 25.6 MB
    unsigned short* h1as = (unsigned short*)alloc(8 * SLAB * 2);   // 25.6 MB
    float* h2 = (float*)alloc((size_t)N_NODES * C_DIM * 4);

    prep_k<<<(F_IN * H_DIM + 255) / 256, 256, 0, stream>>>(ei, flag, W1, w1t, W2, w2t,
                                                           cnt, cur);

    int egrid = (int)((E + 255) / 256);
    hist_k<<<egrid, 256, 0, stream>>>(ei, flag, cnt, E);
    int sgrid = (N_NODES + 511) / 512;   // 98 (<=128 for scan2)
    scan1_k<<<sgrid, 512, 0, stream>>>(cnt, rowoff, bsum, dinv, N_NODES);
    scan2_k<<<1, 128, 0, stream>>>(bsum, sgrid);
    scatter_k<<<egrid, 256, 0, stream>>>(ei, flag, dinv, rowoff, bsum, cur, E, colnorm);

    gemm1_k<<<N_PAD / 128, 512, 0, stream>>>(x, w1t, h1s);
    agg1_k<<<8 * ((N_NODES + 3) / 4), 256, 0, stream>>>(h1s, rowoff, bsum, colnorm,
                                                        dinv, b1, h1as, (int)E);
    gemm2_k<<<(N_NODES + 63) / 64, 256, 0, stream>>>(h1as, w2t, h2);
    agg2_k<<<(N_NODES + 15) / 16, 256, 0, stream>>>(h2, rowoff, bsum, colnorm, dinv,
                                                    b2, out, (int)E);
}

// Round 13
// 238.445 us; speedup vs baseline: 1.4144x; 1.4144x over previous
//
#include <hip/hip_runtime.h>
#include <stdint.h>

#define N_NODES 50000
#define N_PAD   50048     // 391 * 128
#define F_IN 512
#define H_DIM 256
#define C_DIM 16

typedef __attribute__((ext_vector_type(8))) short short8;
typedef __attribute__((ext_vector_type(4))) float f32x4;
typedef __attribute__((ext_vector_type(2))) float f32x2;
typedef __attribute__((ext_vector_type(4))) unsigned short us4;
typedef __attribute__((ext_vector_type(8))) unsigned short us8;

__device__ inline float bf2f(unsigned short u) {
    return __uint_as_float(((uint32_t)u) << 16);
}
__device__ inline unsigned short f2bf(float f) {
    uint32_t u = __float_as_uint(f);
    u += 0x7FFFu + ((u >> 16) & 1u);   // round-to-nearest-even
    return (unsigned short)(u >> 16);
}
__device__ inline unsigned short hx(float f) {   // truncating bf16 (1 op)
    return (unsigned short)(__float_as_uint(f) >> 16);
}
__device__ inline int eidx(const void* p, long long i, int is64) {
    return is64 ? (int)((const long long*)p)[i] : ((const int*)p)[i];
}

// ---- fp8 e4m3 encode/decode (HW cvt on gfx950; software fallback) ----
#if __has_builtin(__builtin_amdgcn_cvt_pk_fp8_f32)
__device__ inline uint8_t f2fp8(float f) {
    int r = __builtin_amdgcn_cvt_pk_fp8_f32(f, f, 0, false);
    return (uint8_t)(r & 0xFF);
}
#else
__device__ inline uint8_t f2fp8(float f) {
    uint32_t u = __float_as_uint(f);
    uint32_t s = (u >> 24) & 0x80u;
    float a = fabsf(f);
    if (a >= 448.f) return (uint8_t)(s | 0x7E);           // saturate
    if (a < 0.015625f) {                                   // denormal: m*2^-9
        int d = (int)rintf(a * 512.f);
        if (d < 8) return (uint8_t)(s | d);
        return (uint8_t)(s | 0x08);                        // rounds to 2^-6
    }
    uint32_t au = u & 0x7FFFFFFFu;
    uint32_t r = au + 0x7FFFFu + ((au >> 20) & 1u);        // RNE to 3 mantissa bits
    uint32_t e = (r >> 23) - 120u;
    uint32_t m = (r >> 20) & 7u;
    if (e > 15u || (e == 15u && m == 7u)) return (uint8_t)(s | 0x7E);
    return (uint8_t)(s | (e << 3) | m);
}
#endif

#if __has_builtin(__builtin_amdgcn_cvt_pk_f32_fp8)
#define FP8CVT(w, hi) __builtin_amdgcn_cvt_pk_f32_fp8((w), (hi))
#else
__device__ inline float fp8b_to_f32(uint32_t v) {
    uint32_t e = (v >> 3) & 0xF, m = v & 7, s = (v >> 7) & 1;
    float r = e ? __uint_as_float(((e + 120u) << 23) | (m << 20))
                : (float)m * 0.001953125f;
    return s ? -r : r;
}
__device__ inline f32x2 FP8CVT(uint32_t w, bool hi) {
    uint32_t b = hi ? (w >> 16) : w;
    f32x2 r;
    r.x = fp8b_to_f32(b & 0xFF);
    r.y = fp8b_to_f32((b >> 8) & 0xFF);
    return r;
}
#endif

// CSR row bounds: rowoff = per-512-chunk exclusive sums, bsum = scanned
// chunk offsets (scanned in-place by scan1's last-finishing block).
__device__ inline int row_beg(const int* ro, const int* bs, int n) {
    return ro[n] + bs[n >> 9];
}
__device__ inline int row_end(const int* ro, const int* bs, int n, int E) {
    return (n + 1 < N_NODES) ? ro[n + 1] + bs[(n + 1) >> 9] : E;
}

// async global->LDS, 16B per lane, linear LDS dest (wave base + lane*16)
#define GLOAD16(gp, lp)                                                       \
    __builtin_amdgcn_global_load_lds(                                         \
        (const __attribute__((address_space(1))) void*)(gp),                  \
        (__attribute__((address_space(3))) void*)(lp), 16, 0, 0)

// ---------- fused prep: detect + W transpose-convert + zero cnt/cur/done ---

__global__ void prep_k(const void* ei, int* flag,
                       const float* w1, unsigned short* w1t,
                       const float* w2, unsigned short* w2t,
                       int* cnt, int* cur, int* done) {
    int i = blockIdx.x * 256 + threadIdx.x;
    if (i == 0) {
        const uint32_t* w = (const uint32_t*)ei;
        int is64 = 1;
        for (int j = 1; j < 128; j += 2)
            if (w[j] != 0u) { is64 = 0; break; }
        *flag = is64;
        *done = 0;
    }
    if (i < N_NODES) { cnt[i] = 0; cur[i] = 0; }
    if (i < F_IN * H_DIM) {
        int k = i / H_DIM, n = i % H_DIM;
        w1t[n * F_IN + k] = f2bf(w1[i]);
    }
    if (i < H_DIM * C_DIM) {
        int k = i / C_DIM, n = i % C_DIM;
        w2t[n * H_DIM + k] = f2bf(w2[i]);
    }
}

// ---------- graph build ----------

__global__ void hist_k(const void* ei, const int* flag, int* cnt, long long E) {
    long long e = (long long)blockIdx.x * 256 + threadIdx.x;
    if (e >= E) return;
    int d = eidx(ei, E + e, *flag);
    atomicAdd(&cnt[d], 1);
}

// per-chunk scan; the LAST block to finish scans bsum in place (r10-proven).
__global__ __launch_bounds__(512) void scan1_k(const int* cnt, int* rowoff, int* bsum,
                                               float* dinv, int* done, int n, int nblk) {
    __shared__ int s[512];
    __shared__ int amLast;
    int t = threadIdx.x;
    int i = blockIdx.x * 512 + t;
    int v = (i < n) ? cnt[i] : 0;
    s[t] = v;
    __syncthreads();
    for (int off = 1; off < 512; off <<= 1) {
        int add = (t >= off) ? s[t - off] : 0;
        __syncthreads();
        s[t] += add;
        __syncthreads();
    }
    if (i < n) {
        rowoff[i] = s[t] - v;                 // exclusive within chunk
        dinv[i] = rsqrtf((float)(v + 1));     // +1 self loop
    }
    if (t == 511) bsum[blockIdx.x] = s[511];
    __threadfence();
    if (t == 0) amLast = (atomicAdd(done, 1) == nblk - 1);
    __syncthreads();
    if (amLast && t == 0) {
        __threadfence();
        volatile int* vb = bsum;
        int run = 0;
        for (int b = 0; b < nblk; ++b) {
            int x = vb[b];
            vb[b] = run;
            run += x;
        }
    }
}

__global__ void scatter_k(const void* ei, const int* flag, const float* dinv,
                          const int* rowoff, const int* bsum, int* cur,
                          long long E, int2* colnorm) {
    long long e = (long long)blockIdx.x * 256 + threadIdx.x;
    if (e >= E) return;
    int is64 = *flag;
    int s = eidx(ei, e, is64);
    int d = eidx(ei, E + e, is64);
    int pos = row_beg(rowoff, bsum, d) + atomicAdd(&cur[d], 1);
    float nrm = dinv[s] * dinv[d];
    int2 cn;
    cn.x = s;
    cn.y = __float_as_int(nrm);
    colnorm[pos] = cn;
}

// ---------- GEMM1: h1(fp8) = e4m3(x @ W1) — r9 counted-vmcnt pipeline ------

__global__ __launch_bounds__(512, 4) void gemm1_k(const float* __restrict__ x,
                                                  const unsigned short* __restrict__ w1t,
                                                  uint8_t* __restrict__ h1) {
    __shared__ __align__(16) float          Asf[2][128 * 32];  // 32 KB
    __shared__ __align__(16) unsigned short Bs[2][256 * 32];   // 32 KB

    const int t = threadIdx.x;
    const int wv = t >> 6, lane = t & 63;
    const int lg = lane >> 4, lr = lane & 15;
    const int wm = wv >> 2, wn = wv & 3;

    const int arow0 = t >> 3;
    const int achk = (t & 7) ^ (arow0 & 7);
    size_t g0 = (size_t)blockIdx.x * 128 + arow0;
    size_t g1 = g0 + 64;
    if (g0 > N_NODES - 1) g0 = N_NODES - 1;
    if (g1 > N_NODES - 1) g1 = N_NODES - 1;
    const float* asrc0 = x + g0 * F_IN + achk * 4;
    const float* asrc1 = x + g1 * F_IN + achk * 4;
    const unsigned short* bsrc0 = w1t + (size_t)(t >> 2) * F_IN + (t & 3) * 8;
    const unsigned short* bsrc1 = bsrc0 + 128 * F_IN;

#define STAGE(bf, ks)                                                         \
    do { const int _o = (ks) * 32;                                            \
        GLOAD16(asrc0 + _o, &Asf[bf][t * 4]);                                 \
        GLOAD16(asrc1 + _o, &Asf[bf][t * 4 + 2048]);                          \
        GLOAD16(bsrc0 + _o, &Bs[bf][t * 8]);                                  \
        GLOAD16(bsrc1 + _o, &Bs[bf][(t + 512) * 8]);                          \
    } while (0)

    f32x4 acc[4][4] = {};

    STAGE(0, 0);                       // 4 outstanding

    for (int ks = 0; ks < 16; ++ks) {
        const int bf = ks & 1;
        if (ks < 15) {
            STAGE(bf ^ 1, ks + 1);     // <=8 outstanding
            asm volatile("s_waitcnt vmcnt(4)" ::: "memory");  // buf-ks landed
        } else {
            asm volatile("s_waitcnt vmcnt(0)" ::: "memory");
        }
        __builtin_amdgcn_sched_barrier(0);
        __builtin_amdgcn_s_barrier();  // bar1: buf-ks visible to all waves

        short8 afr[4], bfr[4];
#pragma unroll
        for (int mi = 0; mi < 4; ++mi) {
            const int r = wm * 64 + mi * 16 + lr;
            const int s = r & 7;
            const float* base = &Asf[bf][r * 32];
            f32x4 lo = *(const f32x4*)(base + (((lg * 2) ^ s) * 4));
            f32x4 hi = *(const f32x4*)(base + (((lg * 2 + 1) ^ s) * 4));
            short8 a;
            a[0] = (short)hx(lo[0]); a[1] = (short)hx(lo[1]);
            a[2] = (short)hx(lo[2]); a[3] = (short)hx(lo[3]);
            a[4] = (short)hx(hi[0]); a[5] = (short)hx(hi[1]);
            a[6] = (short)hx(hi[2]); a[7] = (short)hx(hi[3]);
            afr[mi] = a;
        }
#pragma unroll
        for (int ni = 0; ni < 4; ++ni)
            bfr[ni] = *(const short8*)&Bs[bf][(wn * 64 + ni * 16 + lr) * 32 + lg * 8];
#pragma unroll
        for (int mi = 0; mi < 4; ++mi)
#pragma unroll
            for (int ni = 0; ni < 4; ++ni)
                acc[mi][ni] = __builtin_amdgcn_mfma_f32_16x16x32_bf16(
                    afr[mi], bfr[ni], acc[mi][ni], 0, 0, 0);

        asm volatile("s_waitcnt lgkmcnt(0)" ::: "memory");
        __builtin_amdgcn_sched_barrier(0);
        __builtin_amdgcn_s_barrier();  // bar2: safe to overwrite next buffer
    }
#undef STAGE

    // C layout: col=lane&15, row=(lane>>4)*4+reg; fp8 byte stores
    const size_t rbase = (size_t)blockIdx.x * 128 + wm * 64 + lg * 4;
#pragma unroll
    for (int mi = 0; mi < 4; ++mi)
#pragma unroll
        for (int ni = 0; ni < 4; ++ni) {
            const int col = wn * 64 + ni * 16 + lr;
#pragma unroll
            for (int j = 0; j < 4; ++j)
                h1[(rbase + mi * 16 + j) * H_DIM + col] = f2fp8(acc[mi][ni][j]);
        }
}

// ---------- Aggregation layer 1: h1a = bf16(relu(Anorm@h1fp8+b1)) ----------
// r9 structure: 1 wave per dst node; half-wave (32 lanes x 8B fp8 = full
// 256B row) per edge; halves on even/odd edges (4-deep ILP); shfl_xor(32).
// Decode: HW v_cvt_pk_f32_fp8 (4 cvt + 8 FMA per edge-lane).

__global__ __launch_bounds__(256) void agg1_k(const uint8_t* __restrict__ h1,
                                              const int* __restrict__ rowoff,
                                              const int* __restrict__ bsum,
                                              const int2* __restrict__ colnorm,
                                              const float* __restrict__ dinv,
                                              const float* __restrict__ b1,
                                              unsigned short* __restrict__ h1a,
                                              int E) {
    int wv = threadIdx.x >> 6, lane = threadIdx.x & 63;
    int node = blockIdx.x * 4 + wv;
    if (node >= N_NODES) return;
    int half = lane >> 5;
    int fl = (lane & 31) * 8;               // 8 features per lane
    int beg = row_beg(rowoff, bsum, node);
    int end = row_end(rowoff, bsum, node, E);
    float a[8] = {0.f, 0.f, 0.f, 0.f, 0.f, 0.f, 0.f, 0.f};
    const uint8_t* base = h1 + fl;

#define ACCUM(vv, nn)                                                         \
    do { f32x2 p0 = FP8CVT((vv).x, false), p1 = FP8CVT((vv).x, true);         \
         f32x2 p2 = FP8CVT((vv).y, false), p3 = FP8CVT((vv).y, true);         \
         a[0] += (nn) * p0.x; a[1] += (nn) * p0.y;                            \
         a[2] += (nn) * p1.x; a[3] += (nn) * p1.y;                            \
         a[4] += (nn) * p2.x; a[5] += (nn) * p2.y;                            \
         a[6] += (nn) * p3.x; a[7] += (nn) * p3.y; } while (0)

    int e = beg + half;
    while (e + 6 < end) {                   // 4 edges per half in flight
        int2 c[4];
        uint2 v[4];
#pragma unroll
        for (int q = 0; q < 4; ++q) c[q] = colnorm[e + q * 2];
#pragma unroll
        for (int q = 0; q < 4; ++q)
            v[q] = *(const uint2*)(base + (size_t)c[q].x * H_DIM);
#pragma unroll
        for (int q = 0; q < 4; ++q) {
            float n = __int_as_float(c[q].y);
            ACCUM(v[q], n);
        }
        e += 8;
    }
    while (e < end) {
        int2 c0 = colnorm[e];
        uint2 v0 = *(const uint2*)(base + (size_t)c0.x * H_DIM);
        float n0 = __int_as_float(c0.y);
        ACCUM(v0, n0);
        e += 2;
    }
#undef ACCUM
#pragma unroll
    for (int j = 0; j < 8; ++j)
        a[j] += __shfl_xor(a[j], 32);

    if (half == 0) {
        float dn = dinv[node];
        float sn = dn * dn;
        uint2 vsv = *(const uint2*)(base + (size_t)node * H_DIM);
        f32x2 s0 = FP8CVT(vsv.x, false), s1 = FP8CVT(vsv.x, true);
        f32x2 s2 = FP8CVT(vsv.y, false), s3 = FP8CVT(vsv.y, true);
        float sv[8] = {s0.x, s0.y, s1.x, s1.y, s2.x, s2.y, s3.x, s3.y};
        float4 b0 = *(const float4*)(b1 + fl);
        float4 b4 = *(const float4*)(b1 + fl + 4);
        float bb[8] = {b0.x, b0.y, b0.z, b0.w, b4.x, b4.y, b4.z, b4.w};
        us8 o;
#pragma unroll
        for (int j = 0; j < 8; ++j) {
            float r = fmaxf(a[j] + sn * sv[j] + bb[j], 0.f);
            o[j] = f2bf(r);
        }
        *(us8*)(h1a + (long long)node * H_DIM + fl) = o;
    }
}

// ---------- GEMM2: h2[50000x16] = h1a @ W2 (MFMA straight from global) ----

__global__ __launch_bounds__(256) void gemm2_k(const unsigned short* __restrict__ h1a,
                                               const unsigned short* __restrict__ w2t,
                                               float* __restrict__ h2) {
    int t = threadIdx.x;
    int wv = t >> 6, lane = t & 63, lg = lane >> 4, lr = lane & 15;
    int rbase = blockIdx.x * 64 + wv * 16;
    int rr = rbase + lr;
    int rc = rr < N_NODES ? rr : N_NODES - 1;
    f32x4 acc = {0.f, 0.f, 0.f, 0.f};
#pragma unroll
    for (int ks = 0; ks < 8; ++ks) {
        short8 a = *(const short8*)(h1a + (long long)rc * H_DIM + ks * 32 + lg * 8);
        short8 b = *(const short8*)(w2t + lr * H_DIM + ks * 32 + lg * 8);
        acc = __builtin_amdgcn_mfma_f32_16x16x32_bf16(a, b, acc, 0, 0, 0);
    }
#pragma unroll
    for (int j = 0; j < 4; ++j) {
        int row = rbase + lg * 4 + j;
        if (row < N_NODES) h2[(long long)row * C_DIM + lr] = acc[j];
    }
}

// ---------- Aggregation layer 2: out = A_norm @ h2 + b2 (fp32) ----------

__global__ __launch_bounds__(256) void agg2_k(const float* __restrict__ h2,
                                              const int* __restrict__ rowoff,
                                              const int* __restrict__ bsum,
                                              const int2* __restrict__ colnorm,
                                              const float* __restrict__ dinv,
                                              const float* __restrict__ b2,
                                              float* __restrict__ out, int E) {
    int g = threadIdx.x >> 4, c = threadIdx.x & 15;
    int node = blockIdx.x * 16 + g;
    if (node >= N_NODES) return;
    int beg = row_beg(rowoff, bsum, node);
    int end = row_end(rowoff, bsum, node, E);
    float acc = 0.f;
    int e = beg;
    for (; e + 3 < end; e += 4) {
        int2 cn0 = colnorm[e];
        int2 cn1 = colnorm[e + 1];
        int2 cn2 = colnorm[e + 2];
        int2 cn3 = colnorm[e + 3];
        float v0 = h2[(long long)cn0.x * C_DIM + c];
        float v1 = h2[(long long)cn1.x * C_DIM + c];
        float v2 = h2[(long long)cn2.x * C_DIM + c];
        float v3 = h2[(long long)cn3.x * C_DIM + c];
        acc += __int_as_float(cn0.y) * v0 + __int_as_float(cn1.y) * v1
             + __int_as_float(cn2.y) * v2 + __int_as_float(cn3.y) * v3;
    }
    for (; e < end; ++e) {
        int2 cn = colnorm[e];
        acc += __int_as_float(cn.y) * h2[(long long)cn.x * C_DIM + c];
    }
    float dn = dinv[node];
    acc += dn * dn * h2[(long long)node * C_DIM + c];
    out[(long long)node * C_DIM + c] = acc + b2[c];
}

// ---------- launch ----------

extern "C" void kernel_launch(void* const* d_in, const int* in_sizes, int n_in,
                              void* d_out, int out_size, void* d_ws, size_t ws_size,
                              hipStream_t stream) {
    const float* x  = (const float*)d_in[0];
    const void*  ei = d_in[1];
    const float* W1 = (const float*)d_in[2];
    const float* b1 = (const float*)d_in[3];
    const float* W2 = (const float*)d_in[4];
    const float* b2 = (const float*)d_in[5];
    float* out = (float*)d_out;
    long long E = (long long)in_sizes[1] / 2;

    char* w = (char*)d_ws;
    auto alloc = [&](size_t bytes) -> char* {
        char* p = w;
        w += (bytes + 255) & ~(size_t)255;
        return p;
    };
    int*   flag    = (int*)   alloc(8);        // flag + done
    int*   done    = flag + 1;
    int*   cnt     = (int*)   alloc((size_t)N_NODES * 4);
    int*   cur     = (int*)   alloc((size_t)N_NODES * 4);
    float* dinv    = (float*) alloc((size_t)N_NODES * 4);
    int*   rowoff  = (int*)   alloc((size_t)N_NODES * 4);
    int*   bsum    = (int*)   alloc(512 * 4);
    int2*  colnorm = (int2*)  alloc((size_t)E * 8);
    unsigned short* w1t = (unsigned short*)alloc((size_t)H_DIM * F_IN * 2);
    unsigned short* w2t = (unsigned short*)alloc((size_t)C_DIM * H_DIM * 2);
    uint8_t* h1 = (uint8_t*)alloc((size_t)N_PAD * H_DIM);                      // 12.8 MB
    unsigned short* h1a = (unsigned short*)alloc((size_t)N_NODES * H_DIM * 2); // 25.6 MB
    float* h2 = (float*)alloc((size_t)N_NODES * C_DIM * 4);

    prep_k<<<(F_IN * H_DIM + 255) / 256, 256, 0, stream>>>(ei, flag, W1, w1t, W2, w2t,
                                                           cnt, cur, done);

    int egrid = (int)((E + 255) / 256);
    hist_k<<<egrid, 256, 0, stream>>>(ei, flag, cnt, E);
    int sgrid = (N_NODES + 511) / 512;   // 98
    scan1_k<<<sgrid, 512, 0, stream>>>(cnt, rowoff, bsum, dinv, done, N_NODES, sgrid);
    scatter_k<<<egrid, 256, 0, stream>>>(ei, flag, dinv, rowoff, bsum, cur, E, colnorm);

    gemm1_k<<<N_PAD / 128, 512, 0, stream>>>(x, w1t, h1);
    agg1_k<<<(N_NODES + 3) / 4, 256, 0, stream>>>(h1, rowoff, bsum, colnorm, dinv,
                                                  b1, h1a, (int)E);
    gemm2_k<<<(N_NODES + 63) / 64, 256, 0, stream>>>(h1a, w2t, h2);
    agg2_k<<<(N_NODES + 15) / 16, 256, 0, stream>>>(h2, rowoff, bsum, colnorm, dinv,
                                                    b2, out, (int)E);
}

// Round 14
// 180.959 us; speedup vs baseline: 1.8637x; 1.3177x over previous
//
#include <hip/hip_runtime.h>
#include <stdint.h>

#define N_NODES 50000
#define N_PAD   50048     // 391 * 128
#define F_IN 512
#define H_DIM 256
#define C_DIM 16

typedef __attribute__((ext_vector_type(8))) short short8;
typedef __attribute__((ext_vector_type(4))) float f32x4;
typedef __attribute__((ext_vector_type(2))) float f32x2;
typedef __attribute__((ext_vector_type(4))) unsigned short us4;
typedef __attribute__((ext_vector_type(8))) unsigned short us8;

__device__ inline float bf2f(unsigned short u) {
    return __uint_as_float(((uint32_t)u) << 16);
}
__device__ inline unsigned short f2bf(float f) {
    uint32_t u = __float_as_uint(f);
    u += 0x7FFFu + ((u >> 16) & 1u);   // round-to-nearest-even
    return (unsigned short)(u >> 16);
}
__device__ inline unsigned short hx(float f) {   // truncating bf16 (1 op)
    return (unsigned short)(__float_as_uint(f) >> 16);
}
__device__ inline int eidx(const void* p, long long i, int is64) {
    return is64 ? (int)((const long long*)p)[i] : ((const int*)p)[i];
}

// ---- fp8 e4m3 encode/decode (HW cvt on gfx950; software fallback) ----
#if __has_builtin(__builtin_amdgcn_cvt_pk_fp8_f32)
__device__ inline uint8_t f2fp8(float f) {
    int r = __builtin_amdgcn_cvt_pk_fp8_f32(f, f, 0, false);
    return (uint8_t)(r & 0xFF);
}
#else
__device__ inline uint8_t f2fp8(float f) {
    uint32_t u = __float_as_uint(f);
    uint32_t s = (u >> 24) & 0x80u;
    float a = fabsf(f);
    if (a >= 448.f) return (uint8_t)(s | 0x7E);           // saturate
    if (a < 0.015625f) {                                   // denormal: m*2^-9
        int d = (int)rintf(a * 512.f);
        if (d < 8) return (uint8_t)(s | d);
        return (uint8_t)(s | 0x08);                        // rounds to 2^-6
    }
    uint32_t au = u & 0x7FFFFFFFu;
    uint32_t r = au + 0x7FFFFu + ((au >> 20) & 1u);        // RNE to 3 mantissa bits
    uint32_t e = (r >> 23) - 120u;
    uint32_t m = (r >> 20) & 7u;
    if (e > 15u || (e == 15u && m == 7u)) return (uint8_t)(s | 0x7E);
    return (uint8_t)(s | (e << 3) | m);
}
#endif

#if __has_builtin(__builtin_amdgcn_cvt_pk_f32_fp8)
#define FP8CVT(w, hi) __builtin_amdgcn_cvt_pk_f32_fp8((w), (hi))
#else
__device__ inline float fp8b_to_f32(uint32_t v) {
    uint32_t e = (v >> 3) & 0xF, m = v & 7, s = (v >> 7) & 1;
    float r = e ? __uint_as_float(((e + 120u) << 23) | (m << 20))
                : (float)m * 0.001953125f;
    return s ? -r : r;
}
__device__ inline f32x2 FP8CVT(uint32_t w, bool hi) {
    uint32_t b = hi ? (w >> 16) : w;
    f32x2 r;
    r.x = fp8b_to_f32(b & 0xFF);
    r.y = fp8b_to_f32((b >> 8) & 0xFF);
    return r;
}
#endif

// CSR row bounds: rowoff = per-512-chunk exclusive sums, bsum = scanned
// chunk offsets (scan2).
__device__ inline int row_beg(const int* ro, const int* bs, int n) {
    return ro[n] + bs[n >> 9];
}
__device__ inline int row_end(const int* ro, const int* bs, int n, int E) {
    return (n + 1 < N_NODES) ? ro[n + 1] + bs[(n + 1) >> 9] : E;
}

// async global->LDS, 16B per lane, linear LDS dest (wave base + lane*16)
#define GLOAD16(gp, lp)                                                       \
    __builtin_amdgcn_global_load_lds(                                         \
        (const __attribute__((address_space(1))) void*)(gp),                  \
        (__attribute__((address_space(3))) void*)(lp), 16, 0, 0)

// ---------- fused prep: dtype detect + W transpose-convert + cnt/cur zero --

__global__ void prep_k(const void* ei, int* flag,
                       const float* w1, unsigned short* w1t,
                       const float* w2, unsigned short* w2t,
                       int* cnt, int* cur) {
    int i = blockIdx.x * 256 + threadIdx.x;
    if (i == 0) {
        const uint32_t* w = (const uint32_t*)ei;
        int is64 = 1;
        for (int j = 1; j < 128; j += 2)
            if (w[j] != 0u) { is64 = 0; break; }
        *flag = is64;
    }
    if (i < N_NODES) { cnt[i] = 0; cur[i] = 0; }
    if (i < F_IN * H_DIM) {
        int k = i / H_DIM, n = i % H_DIM;
        w1t[n * F_IN + k] = f2bf(w1[i]);
    }
    if (i < H_DIM * C_DIM) {
        int k = i / C_DIM, n = i % C_DIM;
        w2t[n * H_DIM + k] = f2bf(w2[i]);
    }
}

// ---------- graph build (r9 two-kernel scan: fast, tiny dispatches) --------

__global__ void hist_k(const void* ei, const int* flag, int* cnt, long long E) {
    long long e = (long long)blockIdx.x * 256 + threadIdx.x;
    if (e >= E) return;
    int d = eidx(ei, E + e, *flag);
    atomicAdd(&cnt[d], 1);
}

__global__ __launch_bounds__(512) void scan1_k(const int* cnt, int* rowoff, int* bsum,
                                               float* dinv, int n) {
    __shared__ int s[512];
    int t = threadIdx.x;
    int i = blockIdx.x * 512 + t;
    int v = (i < n) ? cnt[i] : 0;
    s[t] = v;
    __syncthreads();
    for (int off = 1; off < 512; off <<= 1) {
        int add = (t >= off) ? s[t - off] : 0;
        __syncthreads();
        s[t] += add;
        __syncthreads();
    }
    if (i < n) {
        rowoff[i] = s[t] - v;                 // exclusive within chunk
        dinv[i] = rsqrtf((float)(v + 1));     // +1 self loop
    }
    if (t == 511) bsum[blockIdx.x] = s[511];
}

__global__ void scan2_k(int* bsum, int nb) {
    __shared__ int s[128];
    int t = threadIdx.x;
    int v = (t < nb) ? bsum[t] : 0;
    s[t] = v;
    __syncthreads();
    for (int off = 1; off < 128; off <<= 1) {
        int add = (t >= off) ? s[t - off] : 0;
        __syncthreads();
        s[t] += add;
        __syncthreads();
    }
    if (t < nb) bsum[t] = s[t] - v;     // exclusive chunk offsets
}

__global__ void scatter_k(const void* ei, const int* flag, const float* dinv,
                          const int* rowoff, const int* bsum, int* cur,
                          long long E, int2* colnorm) {
    long long e = (long long)blockIdx.x * 256 + threadIdx.x;
    if (e >= E) return;
    int is64 = *flag;
    int s = eidx(ei, e, is64);
    int d = eidx(ei, E + e, is64);
    int pos = row_beg(rowoff, bsum, d) + atomicAdd(&cur[d], 1);
    float nrm = dinv[s] * dinv[d];
    int2 cn;
    cn.x = s;
    cn.y = __float_as_int(nrm);
    colnorm[pos] = cn;
}

// ---------- GEMM1: h1(fp8) = e4m3(x @ W1) — r9 counted-vmcnt pipeline ------

__global__ __launch_bounds__(512, 4) void gemm1_k(const float* __restrict__ x,
                                                  const unsigned short* __restrict__ w1t,
                                                  uint8_t* __restrict__ h1) {
    __shared__ __align__(16) float          Asf[2][128 * 32];  // 32 KB
    __shared__ __align__(16) unsigned short Bs[2][256 * 32];   // 32 KB

    const int t = threadIdx.x;
    const int wv = t >> 6, lane = t & 63;
    const int lg = lane >> 4, lr = lane & 15;
    const int wm = wv >> 2, wn = wv & 3;

    const int arow0 = t >> 3;
    const int achk = (t & 7) ^ (arow0 & 7);
    size_t g0 = (size_t)blockIdx.x * 128 + arow0;
    size_t g1 = g0 + 64;
    if (g0 > N_NODES - 1) g0 = N_NODES - 1;
    if (g1 > N_NODES - 1) g1 = N_NODES - 1;
    const float* asrc0 = x + g0 * F_IN + achk * 4;
    const float* asrc1 = x + g1 * F_IN + achk * 4;
    const unsigned short* bsrc0 = w1t + (size_t)(t >> 2) * F_IN + (t & 3) * 8;
    const unsigned short* bsrc1 = bsrc0 + 128 * F_IN;

#define STAGE(bf, ks)                                                         \
    do { const int _o = (ks) * 32;                                            \
        GLOAD16(asrc0 + _o, &Asf[bf][t * 4]);                                 \
        GLOAD16(asrc1 + _o, &Asf[bf][t * 4 + 2048]);                          \
        GLOAD16(bsrc0 + _o, &Bs[bf][t * 8]);                                  \
        GLOAD16(bsrc1 + _o, &Bs[bf][(t + 512) * 8]);                          \
    } while (0)

    f32x4 acc[4][4] = {};

    STAGE(0, 0);                       // 4 outstanding

    for (int ks = 0; ks < 16; ++ks) {
        const int bf = ks & 1;
        if (ks < 15) {
            STAGE(bf ^ 1, ks + 1);     // <=8 outstanding
            asm volatile("s_waitcnt vmcnt(4)" ::: "memory");  // buf-ks landed
        } else {
            asm volatile("s_waitcnt vmcnt(0)" ::: "memory");
        }
        __builtin_amdgcn_sched_barrier(0);
        __builtin_amdgcn_s_barrier();  // bar1: buf-ks visible to all waves

        short8 afr[4], bfr[4];
#pragma unroll
        for (int mi = 0; mi < 4; ++mi) {
            const int r = wm * 64 + mi * 16 + lr;
            const int s = r & 7;
            const float* base = &Asf[bf][r * 32];
            f32x4 lo = *(const f32x4*)(base + (((lg * 2) ^ s) * 4));
            f32x4 hi = *(const f32x4*)(base + (((lg * 2 + 1) ^ s) * 4));
            short8 a;
            a[0] = (short)hx(lo[0]); a[1] = (short)hx(lo[1]);
            a[2] = (short)hx(lo[2]); a[3] = (short)hx(lo[3]);
            a[4] = (short)hx(hi[0]); a[5] = (short)hx(hi[1]);
            a[6] = (short)hx(hi[2]); a[7] = (short)hx(hi[3]);
            afr[mi] = a;
        }
#pragma unroll
        for (int ni = 0; ni < 4; ++ni)
            bfr[ni] = *(const short8*)&Bs[bf][(wn * 64 + ni * 16 + lr) * 32 + lg * 8];
#pragma unroll
        for (int mi = 0; mi < 4; ++mi)
#pragma unroll
            for (int ni = 0; ni < 4; ++ni)
                acc[mi][ni] = __builtin_amdgcn_mfma_f32_16x16x32_bf16(
                    afr[mi], bfr[ni], acc[mi][ni], 0, 0, 0);

        asm volatile("s_waitcnt lgkmcnt(0)" ::: "memory");
        __builtin_amdgcn_sched_barrier(0);
        __builtin_amdgcn_s_barrier();  // bar2: safe to overwrite next buffer
    }
#undef STAGE

    // C layout: col=lane&15, row=(lane>>4)*4+reg; fp8 byte stores
    const size_t rbase = (size_t)blockIdx.x * 128 + wm * 64 + lg * 4;
#pragma unroll
    for (int mi = 0; mi < 4; ++mi)
#pragma unroll
        for (int ni = 0; ni < 4; ++ni) {
            const int col = wn * 64 + ni * 16 + lr;
#pragma unroll
            for (int j = 0; j < 4; ++j)
                h1[(rbase + mi * 16 + j) * H_DIM + col] = f2fp8(acc[mi][ni][j]);
        }
}

// ---------- Aggregation layer 1: h1a = bf16(relu(Anorm@h1fp8+b1)) ----------
// 1 wave per dst node; half-wave (32 lanes x 8B fp8 = full 256B row) per
// edge; halves on even/odd edges (4-deep ILP); shfl_xor(32) combine.

__global__ __launch_bounds__(256) void agg1_k(const uint8_t* __restrict__ h1,
                                              const int* __restrict__ rowoff,
                                              const int* __restrict__ bsum,
                                              const int2* __restrict__ colnorm,
                                              const float* __restrict__ dinv,
                                              const float* __restrict__ b1,
                                              unsigned short* __restrict__ h1a,
                                              int E) {
    int wv = threadIdx.x >> 6, lane = threadIdx.x & 63;
    int node = blockIdx.x * 4 + wv;
    if (node >= N_NODES) return;
    int half = lane >> 5;
    int fl = (lane & 31) * 8;               // 8 features per lane
    int beg = row_beg(rowoff, bsum, node);
    int end = row_end(rowoff, bsum, node, E);
    float a[8] = {0.f, 0.f, 0.f, 0.f, 0.f, 0.f, 0.f, 0.f};
    const uint8_t* base = h1 + fl;

#define ACCUM(vv, nn)                                                         \
    do { f32x2 p0 = FP8CVT((vv).x, false), p1 = FP8CVT((vv).x, true);         \
         f32x2 p2 = FP8CVT((vv).y, false), p3 = FP8CVT((vv).y, true);         \
         a[0] += (nn) * p0.x; a[1] += (nn) * p0.y;                            \
         a[2] += (nn) * p1.x; a[3] += (nn) * p1.y;                            \
         a[4] += (nn) * p2.x; a[5] += (nn) * p2.y;                            \
         a[6] += (nn) * p3.x; a[7] += (nn) * p3.y; } while (0)

    int e = beg + half;
    while (e + 6 < end) {                   // 4 edges per half in flight
        int2 c[4];
        uint2 v[4];
#pragma unroll
        for (int q = 0; q < 4; ++q) c[q] = colnorm[e + q * 2];
#pragma unroll
        for (int q = 0; q < 4; ++q)
            v[q] = *(const uint2*)(base + (size_t)c[q].x * H_DIM);
#pragma unroll
        for (int q = 0; q < 4; ++q) {
            float n = __int_as_float(c[q].y);
            ACCUM(v[q], n);
        }
        e += 8;
    }
    while (e < end) {
        int2 c0 = colnorm[e];
        uint2 v0 = *(const uint2*)(base + (size_t)c0.x * H_DIM);
        float n0 = __int_as_float(c0.y);
        ACCUM(v0, n0);
        e += 2;
    }
#undef ACCUM
#pragma unroll
    for (int j = 0; j < 8; ++j)
        a[j] += __shfl_xor(a[j], 32);

    if (half == 0) {
        float dn = dinv[node];
        float sn = dn * dn;
        uint2 vsv = *(const uint2*)(base + (size_t)node * H_DIM);
        f32x2 s0 = FP8CVT(vsv.x, false), s1 = FP8CVT(vsv.x, true);
        f32x2 s2 = FP8CVT(vsv.y, false), s3 = FP8CVT(vsv.y, true);
        float sv[8] = {s0.x, s0.y, s1.x, s1.y, s2.x, s2.y, s3.x, s3.y};
        float4 b0 = *(const float4*)(b1 + fl);
        float4 b4 = *(const float4*)(b1 + fl + 4);
        float bb[8] = {b0.x, b0.y, b0.z, b0.w, b4.x, b4.y, b4.z, b4.w};
        us8 o;
#pragma unroll
        for (int j = 0; j < 8; ++j) {
            float r = fmaxf(a[j] + sn * sv[j] + bb[j], 0.f);
            o[j] = f2bf(r);
        }
        *(us8*)(h1a + (long long)node * H_DIM + fl) = o;
    }
}

// ---------- GEMM2: h2[50000x16] = h1a @ W2 (MFMA straight from global) ----

__global__ __launch_bounds__(256) void gemm2_k(const unsigned short* __restrict__ h1a,
                                               const unsigned short* __restrict__ w2t,
                                               float* __restrict__ h2) {
    int t = threadIdx.x;
    int wv = t >> 6, lane = t & 63, lg = lane >> 4, lr = lane & 15;
    int rbase = blockIdx.x * 64 + wv * 16;
    int rr = rbase + lr;
    int rc = rr < N_NODES ? rr : N_NODES - 1;
    f32x4 acc = {0.f, 0.f, 0.f, 0.f};
#pragma unroll
    for (int ks = 0; ks < 8; ++ks) {
        short8 a = *(const short8*)(h1a + (long long)rc * H_DIM + ks * 32 + lg * 8);
        short8 b = *(const short8*)(w2t + lr * H_DIM + ks * 32 + lg * 8);
        acc = __builtin_amdgcn_mfma_f32_16x16x32_bf16(a, b, acc, 0, 0, 0);
    }
#pragma unroll
    for (int j = 0; j < 4; ++j) {
        int row = rbase + lg * 4 + j;
        if (row < N_NODES) h2[(long long)row * C_DIM + lr] = acc[j];
    }
}

// ---------- Aggregation layer 2: out = A_norm @ h2 + b2 (fp32) ----------

__global__ __launch_bounds__(256) void agg2_k(const float* __restrict__ h2,
                                              const int* __restrict__ rowoff,
                                              const int* __restrict__ bsum,
                                              const int2* __restrict__ colnorm,
                                              const float* __restrict__ dinv,
                                              const float* __restrict__ b2,
                                              float* __restrict__ out, int E) {
    int g = threadIdx.x >> 4, c = threadIdx.x & 15;
    int node = blockIdx.x * 16 + g;
    if (node >= N_NODES) return;
    int beg = row_beg(rowoff, bsum, node);
    int end = row_end(rowoff, bsum, node, E);
    float acc = 0.f;
    int e = beg;
    for (; e + 3 < end; e += 4) {
        int2 cn0 = colnorm[e];
        int2 cn1 = colnorm[e + 1];
        int2 cn2 = colnorm[e + 2];
        int2 cn3 = colnorm[e + 3];
        float v0 = h2[(long long)cn0.x * C_DIM + c];
        float v1 = h2[(long long)cn1.x * C_DIM + c];
        float v2 = h2[(long long)cn2.x * C_DIM + c];
        float v3 = h2[(long long)cn3.x * C_DIM + c];
        acc += __int_as_float(cn0.y) * v0 + __int_as_float(cn1.y) * v1
             + __int_as_float(cn2.y) * v2 + __int_as_float(cn3.y) * v3;
    }
    for (; e < end; ++e) {
        int2 cn = colnorm[e];
        acc += __int_as_float(cn.y) * h2[(long long)cn.x * C_DIM + c];
    }
    float dn = dinv[node];
    acc += dn * dn * h2[(long long)node * C_DIM + c];
    out[(long long)node * C_DIM + c] = acc + b2[c];
}

// ---------- launch ----------

extern "C" void kernel_launch(void* const* d_in, const int* in_sizes, int n_in,
                              void* d_out, int out_size, void* d_ws, size_t ws_size,
                              hipStream_t stream) {
    const float* x  = (const float*)d_in[0];
    const void*  ei = d_in[1];
    const float* W1 = (const float*)d_in[2];
    const float* b1 = (const float*)d_in[3];
    const float* W2 = (const float*)d_in[4];
    const float* b2 = (const float*)d_in[5];
    float* out = (float*)d_out;
    long long E = (long long)in_sizes[1] / 2;

    char* w = (char*)d_ws;
    auto alloc = [&](size_t bytes) -> char* {
        char* p = w;
        w += (bytes + 255) & ~(size_t)255;
        return p;
    };
    int*   flag    = (int*)   alloc(4);
    int*   cnt     = (int*)   alloc((size_t)N_NODES * 4);
    int*   cur     = (int*)   alloc((size_t)N_NODES * 4);
    float* dinv    = (float*) alloc((size_t)N_NODES * 4);
    int*   rowoff  = (int*)   alloc((size_t)N_NODES * 4);
    int*   bsum    = (int*)   alloc(512 * 4);
    int2*  colnorm = (int2*)  alloc((size_t)E * 8);
    unsigned short* w1t = (unsigned short*)alloc((size_t)H_DIM * F_IN * 2);
    unsigned short* w2t = (unsigned short*)alloc((size_t)C_DIM * H_DIM * 2);
    uint8_t* h1 = (uint8_t*)alloc((size_t)N_PAD * H_DIM);                      // 12.8 MB
    unsigned short* h1a = (unsigned short*)alloc((size_t)N_NODES * H_DIM * 2); // 25.6 MB
    float* h2 = (float*)alloc((size_t)N_NODES * C_DIM * 4);

    prep_k<<<(F_IN * H_DIM + 255) / 256, 256, 0, stream>>>(ei, flag, W1, w1t, W2, w2t,
                                                           cnt, cur);

    int egrid = (int)((E + 255) / 256);
    hist_k<<<egrid, 256, 0, stream>>>(ei, flag, cnt, E);
    int sgrid = (N_NODES + 511) / 512;   // 98 (<=128 for scan2)
    scan1_k<<<sgrid, 512, 0, stream>>>(cnt, rowoff, bsum, dinv, N_NODES);
    scan2_k<<<1, 128, 0, stream>>>(bsum, sgrid);
    scatter_k<<<egrid, 256, 0, stream>>>(ei, flag, dinv, rowoff, bsum, cur, E, colnorm);

    gemm1_k<<<N_PAD / 128, 512, 0, stream>>>(x, w1t, h1);
    agg1_k<<<(N_NODES + 3) / 4, 256, 0, stream>>>(h1, rowoff, bsum, colnorm, dinv,
                                                  b1, h1a, (int)E);
    gemm2_k<<<(N_NODES + 63) / 64, 256, 0, stream>>>(h1a, w2t, h2);
    agg2_k<<<(N_NODES + 15) / 16, 256, 0, stream>>>(h2, rowoff, bsum, colnorm, dinv,
                                                    b2, out, (int)E);
}